// Round 1
// baseline (390.900 us; speedup 1.0000x reference)
//
#include <hip/hip_runtime.h>
#include <hip/hip_bf16.h>
#include <stdint.h>

#define LL 256
#define DD 256
#define CH 32

typedef __attribute__((ext_vector_type(8))) __bf16 bf16x8;
typedef __attribute__((ext_vector_type(4))) float f32x4;

static __device__ __forceinline__ unsigned short f2bf(float f) {
  __bf16 b = (__bf16)f;                      // RTN fptrunc
  return __builtin_bit_cast(unsigned short, b);
}
static __device__ __forceinline__ float bflo(unsigned int u) { return __uint_as_float(u << 16); }
static __device__ __forceinline__ float bfhi(unsigned int u) { return __uint_as_float(u & 0xffff0000u); }

// ---------------------------------------------------------------------------
// Kernel A: h[b,i,j,c] = mask * relu( z[b,i,j,:] . W1[:,c] + b1[c] ), bf16 out
// z channels permuted: z'[2d] = x_i[d]*x_j[d], z'[2d+1] = |x_i[d]-x_j[d]|
// (W1 rows permuted to match) so one x_i b64 + one x_j b64 LDS read -> 8 z ch.
// MFMA 16x16x32_bf16: A = W1' (reg-cached, M=16 ch half), B = z (16 pairs).
// ---------------------------------------------------------------------------
__global__ __launch_bounds__(256, 2) void bepler_h_kernel(
    const float* __restrict__ x, const int* __restrict__ plen,
    const float* __restrict__ W1, const float* __restrict__ b1,
    unsigned short* __restrict__ hws)
{
  __shared__ unsigned short w1s[16384];    // 32 KB: W1' in frag layout
  __shared__ unsigned short xi[32 * 260];  // +4 pad -> bank rotation 2/row
  __shared__ unsigned short xj[32 * 260];

  const int tid  = threadIdx.x;
  const int lane = tid & 63;
  const int wave = tid >> 6;
  const int b  = blockIdx.z;
  const int i0 = blockIdx.y * 32;
  const int j0 = blockIdx.x * 32;

  // Stage W1' (bf16) in MFMA-A-fragment layout:
  // flat[((s*2+hM)*64 + lane)*8 + t] = W1'[32s + 8*(lane>>4) + t][16*hM + (lane&15)]
  for (int idx = tid; idx < 16384; idx += 256) {
    int t  = idx & 7;
    int l  = (idx >> 3) & 63;
    int hM = (idx >> 9) & 1;
    int s  = idx >> 10;
    int kp = 32 * s + 8 * (l >> 4) + t;               // permuted k index
    int c  = 16 * hM + (l & 15);
    int ko = (kp & 1) ? (DD + (kp >> 1)) : (kp >> 1); // original W1 row
    w1s[idx] = f2bf(W1[ko * CH + c]);
  }
  // Stage x tiles as bf16
  for (int idx = tid; idx < 32 * 256; idx += 256) {
    int r = idx >> 8, d = idx & 255;
    xi[r * 260 + d] = f2bf(x[(size_t)(b * LL + i0 + r) * DD + d]);
    xj[r * 260 + d] = f2bf(x[(size_t)(b * LL + j0 + r) * DD + d]);
  }
  __syncthreads();

  // Preload all 32 A-fragments (W1') into registers: 128 VGPRs
  bf16x8 afrag[16][2];
#pragma unroll
  for (int s = 0; s < 16; ++s) {
#pragma unroll
    for (int hM = 0; hM < 2; ++hM) {
      afrag[s][hM] = *(const bf16x8*)(w1s + ((s * 2 + hM) * 64 + lane) * 8);
    }
  }

  const int len = plen[b];
  const int g   = lane >> 4;
  const int m16 = lane & 15;
  float b1v0[4], b1v1[4];
#pragma unroll
  for (int r = 0; r < 4; ++r) {
    b1v0[r] = b1[g * 4 + r];        // c = (lane>>4)*4 + r        (hM = 0)
    b1v1[r] = b1[16 + g * 4 + r];   // c = 16 + (lane>>4)*4 + r   (hM = 1)
  }

  // 16 units per wave: i_loc = wave*8 + (u>>1), jg = u&1 (16-j group)
  for (int u = 0; u < 16; ++u) {
    const int i_loc = wave * 8 + (u >> 1);
    const int jg    = u & 1;
    const unsigned short* xip = xi + i_loc * 260;            // wave-uniform-ish (broadcast)
    const unsigned short* xjp = xj + (jg * 16 + m16) * 260;  // per-lane row
    f32x4 acc0 = {0.f, 0.f, 0.f, 0.f};
    f32x4 acc1 = {0.f, 0.f, 0.f, 0.f};
#pragma unroll
    for (int s = 0; s < 16; ++s) {
      const int d0 = s * 16 + g * 4;          // 4 f-channels -> 8 z-channels
      uint2 ui = *(const uint2*)(xip + d0);   // ds_read_b64, broadcast in group
      uint2 uj = *(const uint2*)(xjp + d0);   // ds_read_b64, conflict-free (pad)
      float a0 = bflo(ui.x), a1 = bfhi(ui.x), a2 = bflo(ui.y), a3 = bfhi(ui.y);
      float c0 = bflo(uj.x), c1 = bfhi(uj.x), c2 = bflo(uj.y), c3 = bfhi(uj.y);
      bf16x8 bfrag;
      bfrag[0] = (__bf16)(a0 * c0);
      bfrag[1] = (__bf16)fabsf(a0 - c0);
      bfrag[2] = (__bf16)(a1 * c1);
      bfrag[3] = (__bf16)fabsf(a1 - c1);
      bfrag[4] = (__bf16)(a2 * c2);
      bfrag[5] = (__bf16)fabsf(a2 - c2);
      bfrag[6] = (__bf16)(a3 * c3);
      bfrag[7] = (__bf16)fabsf(a3 - c3);
      acc0 = __builtin_amdgcn_mfma_f32_16x16x32_bf16(afrag[s][0], bfrag, acc0, 0, 0, 0);
      acc1 = __builtin_amdgcn_mfma_f32_16x16x32_bf16(afrag[s][1], bfrag, acc1, 0, 0, 0);
    }
    // D layout: c = hM*16 + (lane>>4)*4 + reg, j = j0 + jg*16 + (lane&15)
    const int i = i0 + i_loc;
    const int j = j0 + jg * 16 + m16;
    const float msk = (i < len && j < len) ? 1.f : 0.f;
    unsigned short* hp = hws + ((size_t)(b * LL + i) * LL + j) * CH + g * 4;
    {
      float v0 = fmaxf(acc0[0] + b1v0[0], 0.f) * msk;
      float v1 = fmaxf(acc0[1] + b1v0[1], 0.f) * msk;
      float v2 = fmaxf(acc0[2] + b1v0[2], 0.f) * msk;
      float v3 = fmaxf(acc0[3] + b1v0[3], 0.f) * msk;
      uint2 st;
      st.x = (unsigned)f2bf(v0) | ((unsigned)f2bf(v1) << 16);
      st.y = (unsigned)f2bf(v2) | ((unsigned)f2bf(v3) << 16);
      *(uint2*)hp = st;
    }
    {
      float v0 = fmaxf(acc1[0] + b1v1[0], 0.f) * msk;
      float v1 = fmaxf(acc1[1] + b1v1[1], 0.f) * msk;
      float v2 = fmaxf(acc1[2] + b1v1[2], 0.f) * msk;
      float v3 = fmaxf(acc1[3] + b1v1[3], 0.f) * msk;
      uint2 st;
      st.x = (unsigned)f2bf(v0) | ((unsigned)f2bf(v1) << 16);
      st.y = (unsigned)f2bf(v2) | ((unsigned)f2bf(v3) << 16);
      *(uint2*)(hp + 16) = st;
    }
  }
}

// ---------------------------------------------------------------------------
// Kernel B: out[b,i,j] = mask * ( sum_{di,dj,c} h[b,i+di-3,j+dj-3,c]*W2[di,dj,c] + b2 )
// Thread computes a 1x4 output strip; weights register-cached per (di, 8-ch grp);
// each h position loaded once (uint4 = 8 bf16 ch) and reused across 7 dj taps.
// ---------------------------------------------------------------------------
__global__ __launch_bounds__(256) void bepler_conv_kernel(
    const unsigned short* __restrict__ hws, const float* __restrict__ W2,
    const float* __restrict__ b2, const int* __restrict__ plen,
    float* __restrict__ out)
{
  __shared__ float w2s[49 * 32];
  for (int idx = threadIdx.x; idx < 49 * 32; idx += 256) w2s[idx] = W2[idx];
  __syncthreads();

  const int b   = blockIdx.z;
  const int i   = blockIdx.y * 16 + (threadIdx.x >> 4);
  const int j0  = blockIdx.x * 64 + (threadIdx.x & 15) * 4;
  const int len = plen[b];

  float acc[4] = {0.f, 0.f, 0.f, 0.f};

  for (int di = 0; di < 7; ++di) {
    const int r = i + di - 3;
    if (r < 0 || r >= LL) continue;   // SAME zero padding (rows)
    const unsigned short* hrow = hws + (size_t)(b * LL + r) * LL * CH;
#pragma unroll
    for (int q = 0; q < 4; ++q) {     // 8-channel group
      float w[7][8];
#pragma unroll
      for (int dj = 0; dj < 7; ++dj) {
        const float4 wa = *(const float4*)&w2s[(di * 7 + dj) * 32 + q * 8];
        const float4 wb = *(const float4*)&w2s[(di * 7 + dj) * 32 + q * 8 + 4];
        w[dj][0] = wa.x; w[dj][1] = wa.y; w[dj][2] = wa.z; w[dj][3] = wa.w;
        w[dj][4] = wb.x; w[dj][5] = wb.y; w[dj][6] = wb.z; w[dj][7] = wb.w;
      }
#pragma unroll
      for (int p = 0; p < 10; ++p) {  // halo positions for 4 outputs
        const int jp = j0 - 3 + p;
        float hv[8];
        if (jp >= 0 && jp < LL) {
          uint4 uv = *(const uint4*)(hrow + jp * CH + q * 8);
          hv[0] = bflo(uv.x); hv[1] = bfhi(uv.x);
          hv[2] = bflo(uv.y); hv[3] = bfhi(uv.y);
          hv[4] = bflo(uv.z); hv[5] = bfhi(uv.z);
          hv[6] = bflo(uv.w); hv[7] = bfhi(uv.w);
        } else {
#pragma unroll
          for (int t = 0; t < 8; ++t) hv[t] = 0.f;  // SAME zero padding (cols)
        }
#pragma unroll
        for (int jj = 0; jj < 4; ++jj) {
          const int dj = p - jj;                     // compile-time after unroll
          if (dj >= 0 && dj < 7) {
            float s = 0.f;
#pragma unroll
            for (int t = 0; t < 8; ++t) s = fmaf(hv[t], w[dj][t], s);
            acc[jj] += s;
          }
        }
      }
    }
  }

  const float bias = b2[0];
  float4 o;
  o.x = (i < len && (j0 + 0) < len) ? acc[0] + bias : 0.f;
  o.y = (i < len && (j0 + 1) < len) ? acc[1] + bias : 0.f;
  o.z = (i < len && (j0 + 2) < len) ? acc[2] + bias : 0.f;
  o.w = (i < len && (j0 + 3) < len) ? acc[3] + bias : 0.f;
  *(float4*)(out + (size_t)(b * LL + i) * LL + j0) = o;
}

extern "C" void kernel_launch(void* const* d_in, const int* in_sizes, int n_in,
                              void* d_out, int out_size, void* d_ws, size_t ws_size,
                              hipStream_t stream) {
  const float* x   = (const float*)d_in[0];
  const int*   pl  = (const int*)d_in[1];
  const float* W1  = (const float*)d_in[2];
  const float* b1  = (const float*)d_in[3];
  const float* W2  = (const float*)d_in[4];
  const float* b2  = (const float*)d_in[5];
  float* out = (float*)d_out;
  unsigned short* hws = (unsigned short*)d_ws;  // [8][256][256][32] bf16 = 33.5 MB

  dim3 gA(8, 8, 8);   // (j-tile, i-tile, b)
  bepler_h_kernel<<<gA, dim3(256), 0, stream>>>(x, pl, W1, b1, hws);
  dim3 gB(4, 16, 8);  // (j-tile/64, i-tile/16, b)
  bepler_conv_kernel<<<gB, dim3(256), 0, stream>>>(hws, W2, b2, pl, out);
}

// Round 2
// 175.421 us; speedup vs baseline: 2.2284x; 2.2284x over previous
//
#include <hip/hip_runtime.h>
#include <hip/hip_bf16.h>
#include <stdint.h>

#define LL 256
#define DD 256
#define CH 32

typedef __attribute__((ext_vector_type(8))) __bf16 bf16x8;
typedef __attribute__((ext_vector_type(4))) float f32x4;

static __device__ __forceinline__ unsigned short f2bf(float f) {
  __bf16 b = (__bf16)f;                      // RTN fptrunc
  return __builtin_bit_cast(unsigned short, b);
}
static __device__ __forceinline__ float bflo(unsigned int u) { return __uint_as_float(u << 16); }
static __device__ __forceinline__ float bfhi(unsigned int u) { return __uint_as_float(u & 0xffff0000u); }

// ---------------------------------------------------------------------------
// Kernel A: h[b,i,j,c] = mask * relu( z[b,i,j,:] . W1[:,c] + b1[c] ), bf16 out
// z channels permuted: z'[2d] = x_i[d]*x_j[d], z'[2d+1] = |x_i[d]-x_j[d]|
// (W1 rows permuted to match) so one x_i b64 + one x_j b64 LDS read -> 8 z ch.
// MFMA 16x16x32_bf16: A = W1' (reg-cached, M=16 ch half), B = z (16 pairs).
// ---------------------------------------------------------------------------
#define XPAD 268   // shorts; stride 268 -> bank rotation 6 -> <=2-way on xj b64 reads (free)
__global__ __launch_bounds__(256, 2) void bepler_h_kernel(
    const float* __restrict__ x, const int* __restrict__ plen,
    const float* __restrict__ W1, const float* __restrict__ b1,
    unsigned short* __restrict__ hws)
{
  __shared__ unsigned short w1s[16384];    // 32 KB: W1' in frag layout
  __shared__ unsigned short xi[32 * XPAD];
  __shared__ unsigned short xj[32 * XPAD];

  const int tid  = threadIdx.x;
  const int lane = tid & 63;
  const int wave = tid >> 6;
  const int b  = blockIdx.z;
  const int i0 = blockIdx.y * 32;
  const int j0 = blockIdx.x * 32;

  // Stage W1' (bf16) in MFMA-A-fragment layout:
  // flat[((s*2+hM)*64 + lane)*8 + t] = W1'[32s + 8*(lane>>4) + t][16*hM + (lane&15)]
  for (int idx = tid; idx < 16384; idx += 256) {
    int t  = idx & 7;
    int l  = (idx >> 3) & 63;
    int hM = (idx >> 9) & 1;
    int s  = idx >> 10;
    int kp = 32 * s + 8 * (l >> 4) + t;               // permuted k index
    int c  = 16 * hM + (l & 15);
    int ko = (kp & 1) ? (DD + (kp >> 1)) : (kp >> 1); // original W1 row
    w1s[idx] = f2bf(W1[ko * CH + c]);
  }
  // Stage x tiles as bf16
  for (int idx = tid; idx < 32 * 256; idx += 256) {
    int r = idx >> 8, d = idx & 255;
    xi[r * XPAD + d] = f2bf(x[(size_t)(b * LL + i0 + r) * DD + d]);
    xj[r * XPAD + d] = f2bf(x[(size_t)(b * LL + j0 + r) * DD + d]);
  }
  __syncthreads();

  // Preload all 32 A-fragments (W1') into registers: 128 VGPRs
  bf16x8 afrag[16][2];
#pragma unroll
  for (int s = 0; s < 16; ++s) {
#pragma unroll
    for (int hM = 0; hM < 2; ++hM) {
      afrag[s][hM] = *(const bf16x8*)(w1s + ((s * 2 + hM) * 64 + lane) * 8);
    }
  }

  const int len = plen[b];
  const int g   = lane >> 4;
  const int m16 = lane & 15;
  float b1v0[4], b1v1[4];
#pragma unroll
  for (int r = 0; r < 4; ++r) {
    b1v0[r] = b1[g * 4 + r];        // c = (lane>>4)*4 + r        (hM = 0)
    b1v1[r] = b1[16 + g * 4 + r];   // c = 16 + (lane>>4)*4 + r   (hM = 1)
  }

  // 16 units per wave: i_loc = wave*8 + (u>>1), jg = u&1 (16-j group)
  for (int u = 0; u < 16; ++u) {
    const int i_loc = wave * 8 + (u >> 1);
    const int jg    = u & 1;
    const unsigned short* xip = xi + i_loc * XPAD;           // wave-uniform (broadcast)
    const unsigned short* xjp = xj + (jg * 16 + m16) * XPAD; // per-lane row
    f32x4 acc0 = {0.f, 0.f, 0.f, 0.f};
    f32x4 acc1 = {0.f, 0.f, 0.f, 0.f};
#pragma unroll
    for (int s = 0; s < 16; ++s) {
      const int d0 = s * 16 + g * 4;          // 4 f-channels -> 8 z-channels
      uint2 ui = *(const uint2*)(xip + d0);   // ds_read_b64, broadcast in group
      uint2 uj = *(const uint2*)(xjp + d0);   // ds_read_b64, <=2-way (free)
      float a0 = bflo(ui.x), a1 = bfhi(ui.x), a2 = bflo(ui.y), a3 = bfhi(ui.y);
      float c0 = bflo(uj.x), c1 = bfhi(uj.x), c2 = bflo(uj.y), c3 = bfhi(uj.y);
      bf16x8 bfrag;
      bfrag[0] = (__bf16)(a0 * c0);
      bfrag[1] = (__bf16)fabsf(a0 - c0);
      bfrag[2] = (__bf16)(a1 * c1);
      bfrag[3] = (__bf16)fabsf(a1 - c1);
      bfrag[4] = (__bf16)(a2 * c2);
      bfrag[5] = (__bf16)fabsf(a2 - c2);
      bfrag[6] = (__bf16)(a3 * c3);
      bfrag[7] = (__bf16)fabsf(a3 - c3);
      acc0 = __builtin_amdgcn_mfma_f32_16x16x32_bf16(afrag[s][0], bfrag, acc0, 0, 0, 0);
      acc1 = __builtin_amdgcn_mfma_f32_16x16x32_bf16(afrag[s][1], bfrag, acc1, 0, 0, 0);
    }
    // D layout: c = hM*16 + (lane>>4)*4 + reg, j = j0 + jg*16 + (lane&15)
    const int i = i0 + i_loc;
    const int j = j0 + jg * 16 + m16;
    const float msk = (i < len && j < len) ? 1.f : 0.f;
    unsigned short* hp = hws + ((size_t)(b * LL + i) * LL + j) * CH + g * 4;
    {
      float v0 = fmaxf(acc0[0] + b1v0[0], 0.f) * msk;
      float v1 = fmaxf(acc0[1] + b1v0[1], 0.f) * msk;
      float v2 = fmaxf(acc0[2] + b1v0[2], 0.f) * msk;
      float v3 = fmaxf(acc0[3] + b1v0[3], 0.f) * msk;
      uint2 st;
      st.x = (unsigned)f2bf(v0) | ((unsigned)f2bf(v1) << 16);
      st.y = (unsigned)f2bf(v2) | ((unsigned)f2bf(v3) << 16);
      *(uint2*)hp = st;
    }
    {
      float v0 = fmaxf(acc1[0] + b1v1[0], 0.f) * msk;
      float v1 = fmaxf(acc1[1] + b1v1[1], 0.f) * msk;
      float v2 = fmaxf(acc1[2] + b1v1[2], 0.f) * msk;
      float v3 = fmaxf(acc1[3] + b1v1[3], 0.f) * msk;
      uint2 st;
      st.x = (unsigned)f2bf(v0) | ((unsigned)f2bf(v1) << 16);
      st.y = (unsigned)f2bf(v2) | ((unsigned)f2bf(v3) << 16);
      *(uint2*)(hp + 16) = st;
    }
  }
}

// ---------------------------------------------------------------------------
// Kernel B: out[b,i,j] = mask * ( sum_{di,dj,c} h[..]*W2[di,dj,c] + b2 )
// LDS-tiled: 16x32 output tile per block, halo 22x38x32ch bf16 in LDS (53.6KB,
// 2 blocks/CU). Thread = 2 adjacent j outputs. Weights via wave-uniform global
// loads -> SGPRs (no VGPR cost). LDS layout [q][row][col] 16B granules, col
// stride 39 (odd) -> uniform 8 lanes per 4-bank group (optimal b128 reads).
// ---------------------------------------------------------------------------
#define TROWS 22
#define TCOLS 38
#define TCPAD 39
__global__ __launch_bounds__(256, 2) void bepler_conv_kernel(
    const unsigned short* __restrict__ hws, const float* __restrict__ W2,
    const float* __restrict__ b2, const int* __restrict__ plen,
    float* __restrict__ out)
{
  __shared__ unsigned short htile[4 * TROWS * TCPAD * 8];  // 54,912 B

  const int tid = threadIdx.x;
  const int b   = blockIdx.z;
  const int i0  = blockIdx.y * 16;
  const int j0  = blockIdx.x * 32;

  // Stage halo: idx -> (row, col, q), q fastest => contiguous 16B global reads
  for (int idx = tid; idx < 4 * TROWS * TCOLS; idx += 256) {
    int q   = idx & 3;
    int rc  = idx >> 2;
    int row = rc / TCOLS;
    int col = rc - row * TCOLS;
    int gi = i0 - 3 + row;
    int gj = j0 - 3 + col;
    uint4 v = make_uint4(0u, 0u, 0u, 0u);
    if (gi >= 0 && gi < LL && gj >= 0 && gj < LL)
      v = *(const uint4*)(hws + (((size_t)(b * LL + gi) * LL + gj) * CH + q * 8));
    *(uint4*)(htile + ((q * TROWS + row) * TCPAD + col) * 8) = v;
  }
  __syncthreads();

  const int li = tid >> 4;        // 0..15 output row in tile
  const int lj = (tid & 15) * 2;  // 0..30 output col (pair) in tile

  float acc0 = 0.f, acc1 = 0.f;
  for (int di = 0; di < 7; ++di) {
    const int row = li + di;                  // 0..21
    const float* wdi = W2 + di * 7 * CH;
    for (int q = 0; q < 4; ++q) {
      const unsigned short* hrow = htile + ((q * TROWS + row) * TCPAD) * 8;
      const float* wq = wdi + q * 8;
      float h0[8], h1[8];
      {
        uint4 u = *(const uint4*)(hrow + lj * 8);
        h0[0] = bflo(u.x); h0[1] = bfhi(u.x); h0[2] = bflo(u.y); h0[3] = bfhi(u.y);
        h0[4] = bflo(u.z); h0[5] = bfhi(u.z); h0[6] = bflo(u.w); h0[7] = bfhi(u.w);
      }
#pragma unroll
      for (int dj = 0; dj < 7; ++dj) {
        uint4 u = *(const uint4*)(hrow + (lj + dj + 1) * 8);
        h1[0] = bflo(u.x); h1[1] = bfhi(u.x); h1[2] = bflo(u.y); h1[3] = bfhi(u.y);
        h1[4] = bflo(u.z); h1[5] = bfhi(u.z); h1[6] = bflo(u.w); h1[7] = bfhi(u.w);
        const float* w = wq + dj * CH;        // wave-uniform -> s_load
        float s0 = 0.f, s1 = 0.f;
#pragma unroll
        for (int t = 0; t < 8; ++t) {
          const float wv = w[t];
          s0 = fmaf(h0[t], wv, s0);
          s1 = fmaf(h1[t], wv, s1);
        }
        acc0 += s0; acc1 += s1;
#pragma unroll
        for (int t = 0; t < 8; ++t) h0[t] = h1[t];  // renamed away under unroll
      }
    }
  }

  const int i = i0 + li;
  const int j = j0 + lj;
  const int len = plen[b];
  const float bias = b2[0];
  float2 o;
  o.x = (i < len && (j + 0) < len) ? acc0 + bias : 0.f;
  o.y = (i < len && (j + 1) < len) ? acc1 + bias : 0.f;
  *(float2*)(out + (size_t)(b * LL + i) * LL + j) = o;
}

extern "C" void kernel_launch(void* const* d_in, const int* in_sizes, int n_in,
                              void* d_out, int out_size, void* d_ws, size_t ws_size,
                              hipStream_t stream) {
  const float* x   = (const float*)d_in[0];
  const int*   pl  = (const int*)d_in[1];
  const float* W1  = (const float*)d_in[2];
  const float* b1  = (const float*)d_in[3];
  const float* W2  = (const float*)d_in[4];
  const float* b2  = (const float*)d_in[5];
  float* out = (float*)d_out;
  unsigned short* hws = (unsigned short*)d_ws;  // [8][256][256][32] bf16 = 33.5 MB

  dim3 gA(8, 8, 8);   // (j-tile, i-tile, b)
  bepler_h_kernel<<<gA, dim3(256), 0, stream>>>(x, pl, W1, b1, hws);
  dim3 gB(8, 16, 8);  // (j-tile/32, i-tile/16, b)
  bepler_conv_kernel<<<gB, dim3(256), 0, stream>>>(hws, W2, b2, pl, out);
}

// Round 3
// 130.688 us; speedup vs baseline: 2.9911x; 1.3423x over previous
//
#include <hip/hip_runtime.h>
#include <hip/hip_bf16.h>
#include <stdint.h>

#define LL 256
#define DD 256
#define CH 32

typedef __attribute__((ext_vector_type(2))) _Float16 f16x2;
typedef __attribute__((ext_vector_type(8))) _Float16 halfx8;
typedef __attribute__((ext_vector_type(4))) float f32x4;

static __device__ __forceinline__ uint32_t pk16(float a, float b) {
  f16x2 p; p.x = (_Float16)a; p.y = (_Float16)b;   // RTN casts
  return __builtin_bit_cast(uint32_t, p);
}

// ---------------------------------------------------------------------------
// Kernel P: pack W2 (fp32 HWIO [7][7][32][1]) into f16 pairs, layout
// ((di*4+q)*7+dj)*4 + t  where pair t covers channels q*8+2t, q*8+2t+1.
// Read by conv via wave-uniform s_load.
// ---------------------------------------------------------------------------
__global__ void bepler_pack_w2(const float* __restrict__ W2, uint32_t* __restrict__ w2p) {
  int idx = blockIdx.x * 256 + threadIdx.x;
  if (idx < 784) {
    int t  = idx & 3;
    int dj = (idx >> 2) % 7;
    int qd = (idx >> 2) / 7;     // di*4+q
    int q  = qd & 3;
    int di = qd >> 2;
    int c  = q * 8 + 2 * t;
    w2p[idx] = pk16(W2[(di * 7 + dj) * 32 + c], W2[(di * 7 + dj) * 32 + c + 1]);
  }
}

// ---------------------------------------------------------------------------
// Kernel A: h[b,i,j,c] = mask * relu( z[b,i,j,:] . W1[:,c] + b1[c] ), f16 out.
// z channel permutation (pair-interleaved): within each 4-channel group d0..d0+3:
//   frag t: 0->mul(d0) 1->mul(d0+1) 2->abs(d0) 3->abs(d0+1)
//           4->mul(d0+2) 5->mul(d0+3) 6->abs(d0+2) 7->abs(d0+3)
// so v_pk_mul_f16 / v_pk_add_f16+and results drop straight into frag words.
// MFMA f32_16x16x32_f16: A = W1' (reg-cached), B = z.
// ---------------------------------------------------------------------------
#define XPAD 268   // shorts; row stride 268 -> <=2-way bank aliasing on b64 reads (free)
__global__ __launch_bounds__(256, 2) void bepler_h_kernel(
    const float* __restrict__ x, const int* __restrict__ plen,
    const float* __restrict__ W1, const float* __restrict__ b1,
    _Float16* __restrict__ hws)
{
  __shared__ _Float16 w1s[16384];    // 32 KB: W1' in A-frag layout
  __shared__ _Float16 xi[32 * XPAD];
  __shared__ _Float16 xj[32 * XPAD];

  const int tid  = threadIdx.x;
  const int lane = tid & 63;
  const int wave = tid >> 6;
  const int b  = blockIdx.z;
  const int i0 = blockIdx.y * 32;
  const int j0 = blockIdx.x * 32;

  // Stage W1' (f16) in MFMA-A-fragment layout:
  // flat[((s*2+hM)*64 + l)*8 + t] = W1[ko][16*hM + (l&15)], ko per pair-interleave
  for (int idx = tid; idx < 16384; idx += 256) {
    int t  = idx & 7;
    int l  = (idx >> 3) & 63;
    int hM = (idx >> 9) & 1;
    int s  = idx >> 10;
    int g  = (l >> 4) & 3;
    int d0 = s * 16 + g * 4;
    int base = d0 + ((t >> 2) << 1) + (t & 1);
    int ko = (t & 2) ? (DD + base) : base;   // W1 rows: [0,256)=mul, [256,512)=absdiff
    int c  = 16 * hM + (l & 15);
    w1s[idx] = (_Float16)W1[ko * CH + c];
  }
  // Stage x tiles as f16
  for (int idx = tid; idx < 32 * 256; idx += 256) {
    int r = idx >> 8, d = idx & 255;
    xi[r * XPAD + d] = (_Float16)x[(size_t)(b * LL + i0 + r) * DD + d];
    xj[r * XPAD + d] = (_Float16)x[(size_t)(b * LL + j0 + r) * DD + d];
  }
  __syncthreads();

  // Preload all 32 A-fragments into registers (64 VGPRs)
  halfx8 afrag[16][2];
#pragma unroll
  for (int s = 0; s < 16; ++s) {
#pragma unroll
    for (int hM = 0; hM < 2; ++hM) {
      afrag[s][hM] = *(const halfx8*)(w1s + ((s * 2 + hM) * 64 + lane) * 8);
    }
  }

  const int len = plen[b];
  const int g   = lane >> 4;
  const int m16 = lane & 15;
  float b1v[2][4];
#pragma unroll
  for (int r = 0; r < 4; ++r) {
    b1v[0][r] = b1[g * 4 + r];        // c = (lane>>4)*4 + r        (hM = 0)
    b1v[1][r] = b1[16 + g * 4 + r];   // c = 16 + (lane>>4)*4 + r   (hM = 1)
  }

  for (int iu = 0; iu < 8; ++iu) {
    const int i_loc = wave * 8 + iu;
    const _Float16* xip = xi + i_loc * XPAD;
    f32x4 acc[2][2];
#pragma unroll
    for (int jg = 0; jg < 2; ++jg)
#pragma unroll
      for (int hM = 0; hM < 2; ++hM)
        acc[jg][hM] = (f32x4){0.f, 0.f, 0.f, 0.f};

#pragma unroll
    for (int s = 0; s < 16; ++s) {
      const int d0 = s * 16 + g * 4;
      const uint2 ui = *(const uint2*)(xip + d0);           // broadcast (free)
      const f16x2 a0 = __builtin_bit_cast(f16x2, ui.x);
      const f16x2 a1 = __builtin_bit_cast(f16x2, ui.y);
#pragma unroll
      for (int jg = 0; jg < 2; ++jg) {
        const uint2 uj = *(const uint2*)(xj + (jg * 16 + m16) * XPAD + d0);
        const f16x2 c0 = __builtin_bit_cast(f16x2, uj.x);
        const f16x2 c1 = __builtin_bit_cast(f16x2, uj.y);
        const f16x2 m0 = a0 * c0;                                    // v_pk_mul_f16
        const f16x2 m1 = a1 * c1;
        const uint32_t s0 = __builtin_bit_cast(uint32_t, a0 - c0) & 0x7FFF7FFFu;  // |.|
        const uint32_t s1 = __builtin_bit_cast(uint32_t, a1 - c1) & 0x7FFF7FFFu;
        uint4 bw;
        bw.x = __builtin_bit_cast(uint32_t, m0);
        bw.y = s0;
        bw.z = __builtin_bit_cast(uint32_t, m1);
        bw.w = s1;
        const halfx8 bfrag = __builtin_bit_cast(halfx8, bw);
        acc[jg][0] = __builtin_amdgcn_mfma_f32_16x16x32_f16(afrag[s][0], bfrag, acc[jg][0], 0, 0, 0);
        acc[jg][1] = __builtin_amdgcn_mfma_f32_16x16x32_f16(afrag[s][1], bfrag, acc[jg][1], 0, 0, 0);
      }
    }

    // D layout: c = hM*16 + (lane>>4)*4 + reg, j = j0 + jg*16 + (lane&15)
    const int i = i0 + i_loc;
#pragma unroll
    for (int jg = 0; jg < 2; ++jg) {
      const int j = j0 + jg * 16 + m16;
      const float msk = (i < len && j < len) ? 1.f : 0.f;
      _Float16* hp = hws + ((size_t)(b * LL + i) * LL + j) * CH + g * 4;
#pragma unroll
      for (int hM = 0; hM < 2; ++hM) {
        float v0 = fmaxf(acc[jg][hM][0] + b1v[hM][0], 0.f) * msk;
        float v1 = fmaxf(acc[jg][hM][1] + b1v[hM][1], 0.f) * msk;
        float v2 = fmaxf(acc[jg][hM][2] + b1v[hM][2], 0.f) * msk;
        float v3 = fmaxf(acc[jg][hM][3] + b1v[hM][3], 0.f) * msk;
        uint2 st;
        st.x = pk16(v0, v1);
        st.y = pk16(v2, v3);
        *(uint2*)(hp + hM * 16) = st;
      }
    }
  }
}

// ---------------------------------------------------------------------------
// Kernel B: out[b,i,j] = mask * ( sum_{di,dj,c} h[..]*W2[di,dj,c] + b2 )
// 16x32 tile/block, halo 22x38x32ch f16 in LDS (53.6 KB, 2 blocks/CU).
// Thread = 2 adjacent j outputs; lane map li=wave*4+(l&3), pj=(l>>2)&15 makes
// every 16-lane phase cover all 8 bank groups (row stride 39 granules, mod 8 = 7).
// Weights: packed f16 pairs from global w2p, wave-uniform -> s_load (no LDS, no VGPR).
// Inner: v_pk_fma_f16 into f16-pair accumulators; f32 reduce at the end.
// ---------------------------------------------------------------------------
#define TROWS 22
#define TCOLS 38
#define TCPAD 39
__global__ __launch_bounds__(256, 2) void bepler_conv_kernel(
    const _Float16* __restrict__ hws, const uint32_t* __restrict__ w2p,
    const float* __restrict__ b2, const int* __restrict__ plen,
    float* __restrict__ out)
{
  __shared__ _Float16 htile[4 * TROWS * TCPAD * 8];  // 54,912 B

  const int tid = threadIdx.x;
  const int b   = blockIdx.z;
  const int i0  = blockIdx.y * 16;
  const int j0  = blockIdx.x * 32;

  // Stage halo: idx -> (row, col, q), q fastest => contiguous 64B global reads
  for (int idx = tid; idx < 4 * TROWS * TCOLS; idx += 256) {
    int q   = idx & 3;
    int rc  = idx >> 2;
    int row = rc / TCOLS;
    int col = rc - row * TCOLS;
    int gi = i0 - 3 + row;
    int gj = j0 - 3 + col;
    uint4 v = make_uint4(0u, 0u, 0u, 0u);
    if (gi >= 0 && gi < LL && gj >= 0 && gj < LL)
      v = *(const uint4*)(hws + (((size_t)(b * LL + gi) * LL + gj) * CH + q * 8));
    *(uint4*)(htile + ((q * TROWS + row) * TCPAD + col) * 8) = v;
  }
  __syncthreads();

  const int l    = tid & 63;
  const int wave = tid >> 6;
  const int li = wave * 4 + (l & 3);   // 0..15 output row in tile
  const int pj = (l >> 2) & 15;        // output cols 2*pj, 2*pj+1

  f16x2 acc0[16], acc1[16];
#pragma unroll
  for (int t = 0; t < 16; ++t) { acc0[t] = (f16x2){(_Float16)0, (_Float16)0};
                                 acc1[t] = (f16x2){(_Float16)0, (_Float16)0}; }

  for (int di = 0; di < 7; ++di) {
    const int row = li + di;                  // 0..21
#pragma unroll
    for (int q = 0; q < 4; ++q) {
      const _Float16* hrow = htile + ((q * TROWS + row) * TCPAD) * 8;
      const uint32_t* wq = w2p + (di * 4 + q) * 28;   // uniform -> SGPR
#pragma unroll
      for (int p = 0; p < 8; ++p) {           // halo cols 2*pj .. 2*pj+7
        uint4 u = *(const uint4*)(hrow + (2 * pj + p) * 8);
        f16x2 h0 = __builtin_bit_cast(f16x2, u.x);
        f16x2 h1 = __builtin_bit_cast(f16x2, u.y);
        f16x2 h2 = __builtin_bit_cast(f16x2, u.z);
        f16x2 h3 = __builtin_bit_cast(f16x2, u.w);
        if (p <= 6) {                         // contributes to output jj=0, dj=p
          const uint32_t* w = wq + p * 4;
          acc0[q * 4 + 0] = __builtin_elementwise_fma(h0, __builtin_bit_cast(f16x2, w[0]), acc0[q * 4 + 0]);
          acc0[q * 4 + 1] = __builtin_elementwise_fma(h1, __builtin_bit_cast(f16x2, w[1]), acc0[q * 4 + 1]);
          acc0[q * 4 + 2] = __builtin_elementwise_fma(h2, __builtin_bit_cast(f16x2, w[2]), acc0[q * 4 + 2]);
          acc0[q * 4 + 3] = __builtin_elementwise_fma(h3, __builtin_bit_cast(f16x2, w[3]), acc0[q * 4 + 3]);
        }
        if (p >= 1) {                         // contributes to output jj=1, dj=p-1
          const uint32_t* w = wq + (p - 1) * 4;
          acc1[q * 4 + 0] = __builtin_elementwise_fma(h0, __builtin_bit_cast(f16x2, w[0]), acc1[q * 4 + 0]);
          acc1[q * 4 + 1] = __builtin_elementwise_fma(h1, __builtin_bit_cast(f16x2, w[1]), acc1[q * 4 + 1]);
          acc1[q * 4 + 2] = __builtin_elementwise_fma(h2, __builtin_bit_cast(f16x2, w[2]), acc1[q * 4 + 2]);
          acc1[q * 4 + 3] = __builtin_elementwise_fma(h3, __builtin_bit_cast(f16x2, w[3]), acc1[q * 4 + 3]);
        }
      }
    }
  }

  float s0 = 0.f, s1 = 0.f;
#pragma unroll
  for (int t = 0; t < 16; ++t) {
    s0 += (float)acc0[t].x + (float)acc0[t].y;
    s1 += (float)acc1[t].x + (float)acc1[t].y;
  }

  const int i = i0 + li;
  const int j = j0 + 2 * pj;
  const int len = plen[b];
  const float bias = b2[0];
  float2 o;
  o.x = (i < len && (j + 0) < len) ? s0 + bias : 0.f;
  o.y = (i < len && (j + 1) < len) ? s1 + bias : 0.f;
  *(float2*)(out + (size_t)(b * LL + i) * LL + j) = o;
}

extern "C" void kernel_launch(void* const* d_in, const int* in_sizes, int n_in,
                              void* d_out, int out_size, void* d_ws, size_t ws_size,
                              hipStream_t stream) {
  const float* x   = (const float*)d_in[0];
  const int*   pl  = (const int*)d_in[1];
  const float* W1  = (const float*)d_in[2];
  const float* b1  = (const float*)d_in[3];
  const float* W2  = (const float*)d_in[4];
  const float* b2  = (const float*)d_in[5];
  float* out = (float*)d_out;
  _Float16* hws = (_Float16*)d_ws;              // [8][256][256][32] f16 = 33,554,432 B
  uint32_t* w2p = (uint32_t*)((char*)d_ws + 33554432);  // 784 packed-f16-pair dwords

  bepler_pack_w2<<<dim3(4), dim3(256), 0, stream>>>(W2, w2p);
  dim3 gA(8, 8, 8);   // (j-tile, i-tile, b)
  bepler_h_kernel<<<gA, dim3(256), 0, stream>>>(x, pl, W1, b1, hws);
  dim3 gB(8, 16, 8);  // (j-tile/32, i-tile/16, b)
  bepler_conv_kernel<<<gB, dim3(256), 0, stream>>>(hws, w2p, b2, pl, out);
}

// Round 4
// 118.071 us; speedup vs baseline: 3.3107x; 1.1069x over previous
//
#include <hip/hip_runtime.h>
#include <stdint.h>

#define LL 256
#define DD 256
#define CH 32

typedef __attribute__((ext_vector_type(2))) _Float16 f16x2;
typedef __attribute__((ext_vector_type(8))) _Float16 halfx8;
typedef __attribute__((ext_vector_type(4))) float f32x4;

static __device__ __forceinline__ uint32_t pk16(float a, float b) {
  f16x2 p; p.x = (_Float16)a; p.y = (_Float16)b;   // RTN casts
  return __builtin_bit_cast(uint32_t, p);
}
static __device__ __forceinline__ f16x2 bc2(uint32_t u) { return __builtin_bit_cast(f16x2, u); }
static __device__ __forceinline__ halfx8 bc8(uint4 u) { return __builtin_bit_cast(halfx8, u); }

// ---------------------------------------------------------------------------
// Kernel P: one-time packing.
//  blocks [0,256):   x fp32 -> xf f16 (8 elems/thread, coalesced float4 loads)
//  blocks [256,320): W1 -> w1p f16 in MFMA-A-frag layout with the d-permutation
//    k-step s, lane-group g=(l>>4), frag t:
//      d  = 32*(s>>1) + 8*g + 4*(s&1) + 2*(t>>2) + (t&1)
//      ko = (t&2) ? 256+d (absdiff row) : d (mul row)
//    flat[((s*2+hM)*64 + l)*8 + t] = W1[ko][16*hM + (l&15)]
//  block 320:        W2 -> w2p packed f16 pairs, [(di*4+q)*7+dj]*4 + t,
//                    pair t = channels q*8+2t, q*8+2t+1
// ---------------------------------------------------------------------------
__global__ void bepler_pack(const float* __restrict__ x, const float* __restrict__ W1,
                            const float* __restrict__ W2, _Float16* __restrict__ xf,
                            _Float16* __restrict__ w1p, uint32_t* __restrict__ w2p) {
  const int gid = blockIdx.x * 256 + threadIdx.x;
  if (blockIdx.x < 256) {
    const float4 f0 = ((const float4*)x)[gid * 2];
    const float4 f1 = ((const float4*)x)[gid * 2 + 1];
    uint4 v;
    v.x = pk16(f0.x, f0.y); v.y = pk16(f0.z, f0.w);
    v.z = pk16(f1.x, f1.y); v.w = pk16(f1.z, f1.w);
    ((uint4*)xf)[gid] = v;
  } else if (blockIdx.x < 320) {
    const int idx = gid - 65536;           // 0..16383
    const int t  = idx & 7;
    const int l  = (idx >> 3) & 63;
    const int hM = (idx >> 9) & 1;
    const int s  = idx >> 10;
    const int g  = (l >> 4) & 3;
    const int d  = 32 * (s >> 1) + 8 * g + 4 * (s & 1) + 2 * ((t >> 2) & 1) + (t & 1);
    const int ko = (t & 2) ? (DD + d) : d;
    w1p[idx] = (_Float16)W1[ko * CH + 16 * hM + (l & 15)];
  } else {
    for (int k = threadIdx.x; k < 784; k += 256) {
      const int t  = k & 3;
      const int dj = (k >> 2) % 7;
      const int qd = (k >> 2) / 7;         // di*4+q
      const int q  = qd & 3;
      const int di = qd >> 2;
      const int c  = q * 8 + 2 * t;
      w2p[k] = pk16(W2[(di * 7 + dj) * 32 + c], W2[(di * 7 + dj) * 32 + c + 1]);
    }
  }
}

// ---------------------------------------------------------------------------
// Kernel A: h[b,i,j,c] = mask * relu( z . W1[:,c] + b1[c] ), f16 out.
// afrags from prepacked w1p (global b128, L2-hot, register-resident).
// x tiles f16 in LDS, stride 272 shorts (granule-bank-uniform for b128 reads).
// i-rows processed in pairs: xj b128 shared, 8 independent MFMA acc chains.
// ---------------------------------------------------------------------------
#define XPAD 272
__global__ __launch_bounds__(256, 2) void bepler_h_kernel(
    const _Float16* __restrict__ xf, const int* __restrict__ plen,
    const uint4* __restrict__ w1p4, const float* __restrict__ b1,
    _Float16* __restrict__ hws)
{
  __shared__ _Float16 xi[32 * XPAD];   // 17.4 KB
  __shared__ _Float16 xj[32 * XPAD];

  const int tid  = threadIdx.x;
  const int lane = tid & 63;
  const int wave = tid >> 6;
  const int b  = blockIdx.z;
  const int i0 = blockIdx.y * 32;
  const int j0 = blockIdx.x * 32;
  const int g   = lane >> 4;
  const int m16 = lane & 15;

  // Load all 32 A-fragments from prepacked global (coalesced, L2-hot): 128 VGPR
  uint4 af[16][2];
#pragma unroll
  for (int s = 0; s < 16; ++s) {
#pragma unroll
    for (int hM = 0; hM < 2; ++hM)
      af[s][hM] = w1p4[(s * 2 + hM) * 64 + lane];
  }

  // Stage x tiles (pure uint4 copies from pre-converted xf)
  const _Float16* xfb = xf + (size_t)b * LL * DD;
  for (int idx = tid; idx < 1024; idx += 256) {
    const int r = idx >> 5, cg = idx & 31;
    ((uint4*)(xi + r * XPAD))[cg] = ((const uint4*)(xfb + (i0 + r) * DD))[cg];
    ((uint4*)(xj + r * XPAD))[cg] = ((const uint4*)(xfb + (j0 + r) * DD))[cg];
  }

  const int len = plen[b];
  float b1v[2][4];
#pragma unroll
  for (int r = 0; r < 4; ++r) {
    b1v[0][r] = b1[g * 4 + r];
    b1v[1][r] = b1[16 + g * 4 + r];
  }
  __syncthreads();

  for (int ip = 0; ip < 4; ++ip) {       // i-row pairs
    const int r0 = wave * 8 + 2 * ip;
    const int r1 = r0 + 1;
    f32x4 acc[2][2][2];                  // [rr][jg][hM]
#pragma unroll
    for (int rr = 0; rr < 2; ++rr)
#pragma unroll
      for (int jg = 0; jg < 2; ++jg)
#pragma unroll
        for (int hM = 0; hM < 2; ++hM)
          acc[rr][jg][hM] = (f32x4){0.f, 0.f, 0.f, 0.f};

#pragma unroll
    for (int m = 0; m < 8; ++m) {
      const int doff = 32 * m + 8 * g;
      const uint4 ua0 = *(const uint4*)(xi + r0 * XPAD + doff);  // broadcast b128
      const uint4 ua1 = *(const uint4*)(xi + r1 * XPAD + doff);
#pragma unroll
      for (int jg = 0; jg < 2; ++jg) {
        const uint4 uc = *(const uint4*)(xj + (jg * 16 + m16) * XPAD + doff);
        const f16x2 c0 = bc2(uc.x), c1 = bc2(uc.y), c2 = bc2(uc.z), c3 = bc2(uc.w);
#pragma unroll
        for (int rr = 0; rr < 2; ++rr) {
          const uint4 ua = rr ? ua1 : ua0;
          const f16x2 a0 = bc2(ua.x), a1 = bc2(ua.y), a2 = bc2(ua.z), a3 = bc2(ua.w);
          const f16x2 p0 = a0 * c0, p1 = a1 * c1, p2 = a2 * c2, p3 = a3 * c3;
          const uint32_t s0 = __builtin_bit_cast(uint32_t, a0 - c0) & 0x7FFF7FFFu;
          const uint32_t s1 = __builtin_bit_cast(uint32_t, a1 - c1) & 0x7FFF7FFFu;
          const uint32_t s2 = __builtin_bit_cast(uint32_t, a2 - c2) & 0x7FFF7FFFu;
          const uint32_t s3 = __builtin_bit_cast(uint32_t, a3 - c3) & 0x7FFF7FFFu;
          uint4 be, bo;
          be.x = __builtin_bit_cast(uint32_t, p0); be.y = s0;
          be.z = __builtin_bit_cast(uint32_t, p1); be.w = s1;
          bo.x = __builtin_bit_cast(uint32_t, p2); bo.y = s2;
          bo.z = __builtin_bit_cast(uint32_t, p3); bo.w = s3;
          const halfx8 bE = bc8(be), bO = bc8(bo);
          acc[rr][jg][0] = __builtin_amdgcn_mfma_f32_16x16x32_f16(bc8(af[2 * m][0]),     bE, acc[rr][jg][0], 0, 0, 0);
          acc[rr][jg][1] = __builtin_amdgcn_mfma_f32_16x16x32_f16(bc8(af[2 * m][1]),     bE, acc[rr][jg][1], 0, 0, 0);
          acc[rr][jg][0] = __builtin_amdgcn_mfma_f32_16x16x32_f16(bc8(af[2 * m + 1][0]), bO, acc[rr][jg][0], 0, 0, 0);
          acc[rr][jg][1] = __builtin_amdgcn_mfma_f32_16x16x32_f16(bc8(af[2 * m + 1][1]), bO, acc[rr][jg][1], 0, 0, 0);
        }
      }
    }

    // D layout: c = 16*hM + (lane>>4)*4 + reg ; j = j0 + jg*16 + (lane&15)
#pragma unroll
    for (int rr = 0; rr < 2; ++rr) {
      const int i = i0 + (rr ? r1 : r0);
#pragma unroll
      for (int jg = 0; jg < 2; ++jg) {
        const int j = j0 + jg * 16 + m16;
        const float msk = (i < len && j < len) ? 1.f : 0.f;
        _Float16* hp = hws + ((size_t)(b * LL + i) * LL + j) * CH + g * 4;
#pragma unroll
        for (int hM = 0; hM < 2; ++hM) {
          const f32x4 a = acc[rr][jg][hM];
          uint2 st;
          st.x = pk16(fmaxf(a[0] + b1v[hM][0], 0.f) * msk,
                      fmaxf(a[1] + b1v[hM][1], 0.f) * msk);
          st.y = pk16(fmaxf(a[2] + b1v[hM][2], 0.f) * msk,
                      fmaxf(a[3] + b1v[hM][3], 0.f) * msk);
          *(uint2*)(hp + hM * 16) = st;
        }
      }
    }
  }
}

// ---------------------------------------------------------------------------
// Kernel B: out[b,i,j] = mask * ( sum_{di,dj,c} h[..]*W2[di,dj,c] + b2 )
// 16x32 tile, halo 22x38, staged in TWO q-phases (16 ch each) -> LDS 27.5 KB
// -> 4 blocks/CU, 16 waves/CU at 1024 blocks (one resident pass).
// Weights wave-uniform from packed global -> SGPR. pk-fma f16 accumulators.
// ---------------------------------------------------------------------------
#define TROWS 22
#define TCOLS 38
#define TCPAD 39
__global__ __launch_bounds__(256, 4) void bepler_conv_kernel(
    const _Float16* __restrict__ hws, const uint32_t* __restrict__ w2p,
    const float* __restrict__ b2, const int* __restrict__ plen,
    float* __restrict__ out)
{
  __shared__ _Float16 htile[2 * TROWS * TCPAD * 8];   // 27,456 B

  const int tid = threadIdx.x;
  const int b   = blockIdx.z;
  const int i0  = blockIdx.y * 16;
  const int j0  = blockIdx.x * 32;
  const int l    = tid & 63;
  const int wave = tid >> 6;
  const int li = wave * 4 + (l & 3);   // output row in tile (bank-uniform map)
  const int pj = (l >> 2) & 15;        // output cols 2*pj, 2*pj+1

  float s0 = 0.f, s1 = 0.f;

  for (int ph = 0; ph < 2; ++ph) {     // channel phases: q = 2*ph, 2*ph+1
    for (int idx = tid; idx < TROWS * TCOLS; idx += 256) {
      const int row = idx / TCOLS, col = idx - row * TCOLS;
      const int gi = i0 - 3 + row, gj = j0 - 3 + col;
      uint4 v0 = make_uint4(0u, 0u, 0u, 0u), v1 = v0;
      if (gi >= 0 && gi < LL && gj >= 0 && gj < LL) {
        const uint4* src = (const uint4*)(hws + (((size_t)(b * LL + gi) * LL + gj) * CH + ph * 16));
        v0 = src[0];
        v1 = src[1];
      }
      *(uint4*)(htile + ((0 * TROWS + row) * TCPAD + col) * 8) = v0;
      *(uint4*)(htile + ((1 * TROWS + row) * TCPAD + col) * 8) = v1;
    }
    __syncthreads();

    f16x2 a0[8], a1[8];
#pragma unroll
    for (int t = 0; t < 8; ++t) { a0[t] = (f16x2){(_Float16)0, (_Float16)0};
                                  a1[t] = (f16x2){(_Float16)0, (_Float16)0}; }

    for (int di = 0; di < 7; ++di) {
      const int row = li + di;                  // 0..21
#pragma unroll
      for (int qq = 0; qq < 2; ++qq) {
        const _Float16* hrow = htile + ((qq * TROWS + row) * TCPAD) * 8;
        const uint32_t* wq = w2p + (di * 4 + 2 * ph + qq) * 28;  // uniform -> SGPR
#pragma unroll
        for (int p = 0; p < 8; ++p) {
          const uint4 u = *(const uint4*)(hrow + (2 * pj + p) * 8);
          const f16x2 h0 = bc2(u.x), h1 = bc2(u.y), h2 = bc2(u.z), h3 = bc2(u.w);
          if (p <= 6) {
            const uint32_t* w = wq + p * 4;
            a0[qq * 4 + 0] = __builtin_elementwise_fma(h0, bc2(w[0]), a0[qq * 4 + 0]);
            a0[qq * 4 + 1] = __builtin_elementwise_fma(h1, bc2(w[1]), a0[qq * 4 + 1]);
            a0[qq * 4 + 2] = __builtin_elementwise_fma(h2, bc2(w[2]), a0[qq * 4 + 2]);
            a0[qq * 4 + 3] = __builtin_elementwise_fma(h3, bc2(w[3]), a0[qq * 4 + 3]);
          }
          if (p >= 1) {
            const uint32_t* w = wq + (p - 1) * 4;
            a1[qq * 4 + 0] = __builtin_elementwise_fma(h0, bc2(w[0]), a1[qq * 4 + 0]);
            a1[qq * 4 + 1] = __builtin_elementwise_fma(h1, bc2(w[1]), a1[qq * 4 + 1]);
            a1[qq * 4 + 2] = __builtin_elementwise_fma(h2, bc2(w[2]), a1[qq * 4 + 2]);
            a1[qq * 4 + 3] = __builtin_elementwise_fma(h3, bc2(w[3]), a1[qq * 4 + 3]);
          }
        }
      }
    }

#pragma unroll
    for (int t = 0; t < 8; ++t) {
      s0 += (float)a0[t].x + (float)a0[t].y;
      s1 += (float)a1[t].x + (float)a1[t].y;
    }
    __syncthreads();   // before next phase overwrites htile
  }

  const int i = i0 + li;
  const int j = j0 + 2 * pj;
  const int len = plen[b];
  const float bias = b2[0];
  float2 o;
  o.x = (i < len && (j + 0) < len) ? s0 + bias : 0.f;
  o.y = (i < len && (j + 1) < len) ? s1 + bias : 0.f;
  *(float2*)(out + (size_t)(b * LL + i) * LL + j) = o;
}

extern "C" void kernel_launch(void* const* d_in, const int* in_sizes, int n_in,
                              void* d_out, int out_size, void* d_ws, size_t ws_size,
                              hipStream_t stream) {
  const float* x   = (const float*)d_in[0];
  const int*   pl  = (const int*)d_in[1];
  const float* W1  = (const float*)d_in[2];
  const float* b1  = (const float*)d_in[3];
  const float* W2  = (const float*)d_in[4];
  const float* b2  = (const float*)d_in[5];
  float* out = (float*)d_out;

  _Float16* hws = (_Float16*)d_ws;                            // 33,554,432 B
  _Float16* w1p = (_Float16*)((char*)d_ws + 33554432);        // 32,768 B
  uint32_t* w2p = (uint32_t*)((char*)d_ws + 33587200);        // 3,136 B
  _Float16* xf  = (_Float16*)((char*)d_ws + 33591296);        // 1,048,576 B

  bepler_pack<<<dim3(321), dim3(256), 0, stream>>>(x, W1, W2, xf, w1p, w2p);
  dim3 gA(8, 8, 8);    // (j-tile/32, i-tile/32, b)
  bepler_h_kernel<<<gA, dim3(256), 0, stream>>>(xf, pl, (const uint4*)w1p, b1, hws);
  dim3 gB(8, 16, 8);   // (j-tile/32, i-tile/16, b)
  bepler_conv_kernel<<<gB, dim3(256), 0, stream>>>(hws, w2p, b2, pl, out);
}